// Round 3
// baseline (722.327 us; speedup 1.0000x reference)
//
#include <hip/hip_runtime.h>
#include <stdint.h>

#define K_DIM 4096
#define N_DIM 4096
#define KS_DIM (K_DIM / 32)   // 128 k-steps
#define NT_DIM (N_DIM / 16)   // 256 n-tiles

typedef __attribute__((ext_vector_type(8))) short s16x8;
typedef __attribute__((ext_vector_type(4))) float f32x4;

static __device__ __forceinline__ unsigned short f32_to_bf16(float f) {
    union { float f; unsigned int u; } v; v.f = f;
    unsigned int u = v.u;
    u += 0x7FFFu + ((u >> 16) & 1u);   // RNE; inputs finite
    return (unsigned short)(u >> 16);
}

static __device__ __forceinline__ s16x8 cvt8(float4 a, float4 b) {
    s16x8 o;
    o[0] = (short)f32_to_bf16(a.x); o[1] = (short)f32_to_bf16(a.y);
    o[2] = (short)f32_to_bf16(a.z); o[3] = (short)f32_to_bf16(a.w);
    o[4] = (short)f32_to_bf16(b.x); o[5] = (short)f32_to_bf16(b.y);
    o[6] = (short)f32_to_bf16(b.z); o[7] = (short)f32_to_bf16(b.w);
    return o;
}

// ---------------------------------------------------------------------------
// Fragment pack layout (B operand): for 16x16x32 bf16 MFMA, lane L holds
// op[n = L&15][k = (L>>4)*8 + j], j=0..7.  Each (nt, ks) fragment stored as
// 64 lane-chunks of 16 B in lane order => LDS image after global_load_lds is
// base + L*16 => fragment ds_read is perfectly linear (conflict-free).
// A fragments use the same LDS image but are produced in-kernel from f32 x.
// ---------------------------------------------------------------------------

// w_t (K,N) f32 -> B-pack via LDS transpose. Block handles 64k x 64n.
extern "C" __global__ void pack_w_k(const float* __restrict__ in,
                                    unsigned short* __restrict__ out) {
    __shared__ __align__(16) unsigned short tile[64][72];  // [n_local][k_local]
    int n0 = blockIdx.x * 64, k0 = blockIdx.y * 64;
    int t = threadIdx.x;
    int tr = t >> 4, tc = (t & 15) * 4;
#pragma unroll
    for (int i = 0; i < 4; ++i) {
        int k = tr + i * 16;
        float4 v = *(const float4*)(in + (size_t)(k0 + k) * N_DIM + n0 + tc);
        tile[tc + 0][k] = f32_to_bf16(v.x);
        tile[tc + 1][k] = f32_to_bf16(v.y);
        tile[tc + 2][k] = f32_to_bf16(v.z);
        tile[tc + 3][k] = f32_to_bf16(v.w);
    }
    __syncthreads();
    int f = t >> 5, h = f >> 2, ntl = f & 3;
    int ks = blockIdx.y * 2 + h;
    int nt = blockIdx.x * 4 + ntl;
    unsigned short* dst = out + ((size_t)(ks * NT_DIM + nt) * 64) * 8;
#pragma unroll
    for (int u = 0; u < 2; ++u) {
        int c = (t & 31) * 2 + u;
        int r = c & 15, q = c >> 4;
        s16x8 o = *(const s16x8*)&tile[ntl * 16 + r][h * 32 + q * 8];
        *(s16x8*)(dst + (size_t)c * 8) = o;
    }
}

__device__ __forceinline__ void async_cp16(const unsigned short* g, unsigned short* l) {
    __builtin_amdgcn_global_load_lds(
        (const __attribute__((address_space(1))) unsigned int*)g,
        (__attribute__((address_space(3))) unsigned int*)l, 16, 0, 0);
}

// ---------------------------------------------------------------------------
// Fused GEMM: A read directly from f32 x (reg-staged + inline RNE cvt, T14),
// B from pack via global_load_lds.  256x256 tile, BK=32, 8 waves (2M x 4N).
// 4-slot LDS ring, counted vmcnt (never 0 in steady state), 2 barriers/tile.
// Every wave stages 2 A-frags (tile t+2, regs) + 2 B-frags (tile t+3, DMA).
// Per-body VMEM issue order (fenced with sched_barrier):
//   I_t = [A(2) ph1, B(1) ph1, A(2) ph2, B(1) ph2]
// ph2 wait vmcnt(7) steady: leaves I_{t-1}[5] + I_t pending => A(t+1) regs
// ready AND B(t+1) cp16s (issued body t-2) complete; barrier then publishes
// tile t+1 (A half ds_written this body, B half DMA'd).
// Slot safety: A-write of tile t+1 -> slot (t+1)&3 (last read body t-3);
// B-DMA of tile t+3 -> slot (t+3)&3 (last read body t-1, >=1 barrier ago).
// ---------------------------------------------------------------------------
#define SLOTS 4
#define SLOT_SHORTS (32 * 512)   // 32 KB per K-tile (16 A + 16 B frags)

__device__ __forceinline__ void sbar() {
    __builtin_amdgcn_sched_barrier(0);
    __builtin_amdgcn_s_barrier();
    __builtin_amdgcn_sched_barrier(0);
}

template <int VM>
__device__ __forceinline__ void wait_vm() {
    if constexpr (VM == 8)      asm volatile("s_waitcnt vmcnt(8)" ::: "memory");
    else if constexpr (VM == 7) asm volatile("s_waitcnt vmcnt(7)" ::: "memory");
    else if constexpr (VM == 6) asm volatile("s_waitcnt vmcnt(6)" ::: "memory");
    else if constexpr (VM == 5) asm volatile("s_waitcnt vmcnt(5)" ::: "memory");
    else if constexpr (VM == 0) asm volatile("s_waitcnt vmcnt(0)" ::: "memory");
    if constexpr (VM >= 0) __builtin_amdgcn_sched_barrier(0);
}

__device__ __forceinline__ void lgkm0() {
    asm volatile("s_waitcnt lgkmcnt(0)" ::: "memory");
    __builtin_amdgcn_sched_barrier(0);
}

// RI: reg set receiving A(t+2); RC: reg set holding A(t+1) to convert+write.
#define BODY(T, RI, RC, VM, SA, SB, CW)                                     \
  {                                                                         \
    const unsigned short* a = lds + ((T) & 3) * SLOT_SHORTS + aOff;         \
    const unsigned short* b = lds + ((T) & 3) * SLOT_SHORTS + bOff;         \
    unsigned short* dB = lds + (((T) + 3) & 3) * SLOT_SHORTS + dsB;         \
    /* ---- phase 1 ---- */                                                 \
    s16x8 af[4], bf[4];                                                     \
    _Pragma("unroll")                                                       \
    for (int i = 0; i < 4; ++i) af[i] = *(const s16x8*)(a + i * 512);       \
    _Pragma("unroll")                                                       \
    for (int j = 0; j < 4; ++j) bf[j] = *(const s16x8*)(b + j * 512);       \
    if (SA) {                                                               \
      RI[0] = *(const float4*)gA0;                                          \
      RI[1] = *(const float4*)(gA0 + 4);                                    \
    }                                                                       \
    __builtin_amdgcn_sched_barrier(0);                                      \
    if (SB) async_cp16(gB, dB);                                             \
    sbar();                                                                 \
    lgkm0();                                                                \
    __builtin_amdgcn_s_setprio(1);                                          \
    _Pragma("unroll")                                                       \
    for (int i = 0; i < 4; ++i)                                             \
      _Pragma("unroll")                                                     \
      for (int j = 0; j < 4; ++j)                                           \
        acc[i][j] = __builtin_amdgcn_mfma_f32_16x16x32_bf16(                \
            af[i], bf[j], acc[i][j], 0, 0, 0);                              \
    __builtin_amdgcn_s_setprio(0);                                          \
    /* ---- phase 2 ---- */                                                 \
    s16x8 ag[4];                                                            \
    _Pragma("unroll")                                                       \
    for (int i = 0; i < 4; ++i) ag[i] = *(const s16x8*)(a + (4 + i) * 512); \
    if (SA) {                                                               \
      RI[2] = *(const float4*)gA1;                                          \
      RI[3] = *(const float4*)(gA1 + 4);                                    \
      gA0 += 32; gA1 += 32;                                                 \
    }                                                                       \
    __builtin_amdgcn_sched_barrier(0);                                      \
    if (SB) { async_cp16(gB + 512, dB + 512); gB += (size_t)NT_DIM * 512; } \
    __builtin_amdgcn_sched_barrier(0);                                      \
    wait_vm<VM>();                                                          \
    if (CW) {                                                               \
      s16x8 o0 = cvt8(RC[0], RC[1]);                                        \
      s16x8 o1 = cvt8(RC[2], RC[3]);                                        \
      unsigned short* wv =                                                  \
          lds + (((T) + 1) & 3) * SLOT_SHORTS + dsA + lane * 8;             \
      *(s16x8*)wv = o0;                                                     \
      *(s16x8*)(wv + 512) = o1;                                             \
    }                                                                       \
    lgkm0();   /* drain A-writes (and ag reads) before publishing barrier */\
    sbar();                                                                 \
    __builtin_amdgcn_s_setprio(1);                                          \
    _Pragma("unroll")                                                       \
    for (int i = 0; i < 4; ++i)                                             \
      _Pragma("unroll")                                                     \
      for (int j = 0; j < 4; ++j)                                           \
        acc[4 + i][j] = __builtin_amdgcn_mfma_f32_16x16x32_bf16(            \
            ag[i], bf[j], acc[4 + i][j], 0, 0, 0);                          \
    __builtin_amdgcn_s_setprio(0);                                          \
  }

extern "C" __global__ __launch_bounds__(512, 2)
void gemm_pk(const float* __restrict__ X,
             const unsigned short* __restrict__ Bp,
             float* __restrict__ C, int M) {
    __shared__ __align__(16) unsigned short lds[SLOTS * SLOT_SHORTS];  // 128 KB
    const int tid = threadIdx.x;
    const int wave = tid >> 6, lane = tid & 63;

    // T1: bijective XCD-aware swizzle of the linear block id (nwg % 8 == 0)
    const int nwg = gridDim.x;
    const int cpx = nwg >> 3;
    const int swz = (blockIdx.x & 7) * cpx + (blockIdx.x >> 3);
    const int bn = swz & (N_DIM / 256 - 1);   // N/256 = 16
    const int bm = swz >> 4;

    const int wm2 = wave >> 2;   // m-half for compute
    const int wn4 = wave & 3;    // n-quarter for compute

    // compute-read bases (lane-linear => conflict-free b128)
    const int aOff = (wm2 * 8) * 512 + lane * 8;
    const int bOff = (16 + wn4 * 4) * 512 + lane * 8;

    // staging: wave stages A-frags {2w,2w+1} (rows 32w..32w+31) and
    // B-frags {2w,2w+1}
    const int dsA = (wave * 2) * 512;
    const int dsB = (16 + wave * 2) * 512;
    const float* gA0 = X + (size_t)(bm * 256 + wave * 32 + (lane & 15)) * K_DIM
                         + ((lane >> 4) * 8);
    const float* gA1 = gA0 + (size_t)16 * K_DIM;
    const unsigned short* gB =
        Bp + (((size_t)bn * 16 + wave * 2) * 64 + lane) * 8;

    f32x4 acc[8][4] = {};
    float4 r0[4], r1[4];

    // ---- prologue ----
    // A tile 0 -> r0 (consumed immediately)
    r0[0] = *(const float4*)gA0; r0[1] = *(const float4*)(gA0 + 4);
    r0[2] = *(const float4*)gA1; r0[3] = *(const float4*)(gA1 + 4);
    gA0 += 32; gA1 += 32;
    __builtin_amdgcn_sched_barrier(0);
    // B tiles 0..2 via DMA (6 cp16)
#pragma unroll
    for (int tt = 0; tt < 3; ++tt) {
        unsigned short* d = lds + tt * SLOT_SHORTS + dsB;
        async_cp16(gB, d);
        async_cp16(gB + 512, d + 512);
        gB += (size_t)NT_DIM * 512;
    }
    __builtin_amdgcn_sched_barrier(0);
    wait_vm<6>();                       // A0 done (6 cp16 pending)
    {
        s16x8 o0 = cvt8(r0[0], r0[1]);
        s16x8 o1 = cvt8(r0[2], r0[3]);
        unsigned short* wv = lds + dsA + lane * 8;   // slot 0
        *(s16x8*)wv = o0;
        *(s16x8*)(wv + 512) = o1;
    }
    // A tile 1 -> r1
    r1[0] = *(const float4*)gA0; r1[1] = *(const float4*)(gA0 + 4);
    r1[2] = *(const float4*)gA1; r1[3] = *(const float4*)(gA1 + 4);
    gA0 += 32; gA1 += 32;
    __builtin_amdgcn_sched_barrier(0);
    wait_vm<8>();                       // B0 (oldest 2 of 10) complete
    lgkm0();                            // A0 ds_writes drained
    sbar();                             // tile 0 published

    // ---- main loop ----
    // body t: issues A(t+2) into set t&1, consumes A(t+1) from set (t+1)&1
    BODY(0, r0, r1, 6, 1, 1, 1);        // special vmcnt: prologue queue shape
    for (int t = 1; t < 125; t += 2) {
        BODY(t,     r1, r0, 7, 1, 1, 1);
        BODY(t + 1, r0, r1, 7, 1, 1, 1);
    }
    BODY(125, r1, r0, 5, 1, 0, 1);      // last A issue (tile 127); no B
    BODY(126, r0, r1, 0, 0, 0, 1);      // consume+write tile 127
    BODY(127, r1, r0, -1, 0, 0, 0);     // pure compute

    // epilogue: C/D layout col=lane&15, row=(lane>>4)*4+reg (m89-verified)
    const size_t tileM = (size_t)bm * 256, tileN = (size_t)bn * 256;
#pragma unroll
    for (int i = 0; i < 8; ++i)
#pragma unroll
        for (int j = 0; j < 4; ++j) {
            size_t row = tileM + wm2 * 128 + i * 16 + (lane >> 4) * 4;
            size_t col = tileN + wn4 * 64 + j * 16 + (lane & 15);
#pragma unroll
            for (int r = 0; r < 4; ++r)
                C[(row + r) * N_DIM + col] = acc[i][j][r];
        }
}

// ---- fallback (ws too small): convert f32->bf16 inline while staging ----
extern "C" __global__ __launch_bounds__(256)
void gemm_f32_k(const float* __restrict__ X,   // (M,K)
                const float* __restrict__ Wt,  // (K,N)
                float* __restrict__ C, int M) {
    const int K = K_DIM, N = N_DIM;
    __shared__ __align__(16) unsigned short sA[128 * 32];
    __shared__ __align__(16) unsigned short sB[128 * 32];
    const int tid = threadIdx.x;
    const int wave = tid >> 6, lane = tid & 63;
    const int wm = (wave >> 1) * 64, wn = (wave & 1) * 64;
    const size_t tileM = (size_t)blockIdx.y * 128, tileN = (size_t)blockIdx.x * 128;
    const int frow = lane & 15, fcol = (lane >> 4) * 8;
    f32x4 acc[4][4] = {};
    for (int k0 = 0; k0 < K; k0 += 32) {
        __syncthreads();
#pragma unroll
        for (int it = 0; it < 4; ++it) {
            int idx = it * 256 + tid;
            int m = idx >> 3, c4 = (idx & 7) * 4;
            float4 v = *(const float4*)(X + (tileM + m) * (size_t)K + k0 + c4);
            sA[m * 32 + c4 + 0] = f32_to_bf16(v.x);
            sA[m * 32 + c4 + 1] = f32_to_bf16(v.y);
            sA[m * 32 + c4 + 2] = f32_to_bf16(v.z);
            sA[m * 32 + c4 + 3] = f32_to_bf16(v.w);
        }
#pragma unroll
        for (int it = 0; it < 16; ++it) {
            int idx = it * 256 + tid;
            int k = idx >> 7, n = idx & 127;
            float v = Wt[(size_t)(k0 + k) * N + tileN + n];
            sB[n * 32 + k] = f32_to_bf16(v);
        }
        __syncthreads();
        s16x8 af[4], bfr[4];
#pragma unroll
        for (int i = 0; i < 4; ++i)
            af[i] = *(const s16x8*)(sA + (wm + i * 16 + frow) * 32 + fcol);
#pragma unroll
        for (int j = 0; j < 4; ++j)
            bfr[j] = *(const s16x8*)(sB + (wn + j * 16 + frow) * 32 + fcol);
#pragma unroll
        for (int i = 0; i < 4; ++i)
#pragma unroll
            for (int j = 0; j < 4; ++j)
                acc[i][j] = __builtin_amdgcn_mfma_f32_16x16x32_bf16(
                    af[i], bfr[j], acc[i][j], 0, 0, 0);
    }
#pragma unroll
    for (int i = 0; i < 4; ++i)
#pragma unroll
        for (int j = 0; j < 4; ++j) {
            size_t row = tileM + wm + i * 16 + (lane >> 4) * 4;
            size_t col = tileN + wn + j * 16 + (lane & 15);
#pragma unroll
            for (int r = 0; r < 4; ++r)
                C[(row + r) * N + col] = acc[i][j][r];
        }
}

extern "C" void kernel_launch(void* const* d_in, const int* in_sizes, int n_in,
                              void* d_out, int out_size, void* d_ws, size_t ws_size,
                              hipStream_t stream) {
    const float* x   = (const float*)d_in[0];
    const float* w_t = (const float*)d_in[4];   // (K,N) dequantized W^T, bit-exact
    float* out = (float*)d_out;
    const int K = K_DIM, N = N_DIM;
    const int M = in_sizes[0] / K;              // 8192
    const size_t need = (size_t)N * K * 2;      // 32 MB (B-pack only)
    if (ws_size >= need && (M % 256) == 0) {
        unsigned short* bp = (unsigned short*)d_ws;
        hipLaunchKernelGGL(pack_w_k, dim3(N / 64, K / 64), dim3(256), 0, stream,
                           w_t, bp);
        hipLaunchKernelGGL(gemm_pk, dim3((M / 256) * (N / 256)), dim3(512), 0,
                           stream, x, bp, out, M);
    } else {
        hipLaunchKernelGGL(gemm_f32_k, dim3(N / 128, M / 128), dim3(256), 0, stream,
                           x, w_t, out, M);
    }
}